// Round 7
// baseline (180.521 us; speedup 1.0000x reference)
//
#include <hip/hip_runtime.h>
#include <hip/hip_bf16.h>

// Attention: xq/xk/xv [2,2048,768] f32, W* [768,768] f32 ([out,in]), bp [768] f32.
// Pipeline: fused cast->bf16, fused QKV NT-GEMM (r15: m97-structure 128x128
// tiles, BK=64, 4 waves x 64x64, 8 ds_read -> 16 MFMA per ks, 576 blocks,
// XCD-swizzled, 2-phase overlap schedule; scale*log2e folded into Q; V
// computed TRANSPOSED via swapped operands), flash attention (r14 structure:
// 32x32 MFMA in-register P + overlap schedule), output NT-GEMM + bias
// (64x96 tiles, BK=128, overlap schedule). LDS XOR-swizzled everywhere.

#define NSEQ 2048
#define CDIM 768
#define NH   12
#define HD   64
#define MTOT 4096            // B*NSEQ
#define XEL  (MTOT*CDIM)     // 3145728
#define WEL  (CDIM*CDIM)     // 589824
#define X8   (XEL/8)         // 393216
#define W8   (WEL/8)         // 73728
#define QSCALE 0.18033688011112042f   // 0.125 * log2(e); scores consumed by exp2

typedef __attribute__((ext_vector_type(8))) short bf16x8;
typedef __attribute__((ext_vector_type(4))) float floatx4;
typedef __attribute__((ext_vector_type(16))) float floatx16;
typedef __attribute__((ext_vector_type(4))) unsigned int uintx4;

// scalar f32->bf16, round-half-up (2 VALU)
static __device__ __forceinline__ unsigned short f2bf(float f) {
  union { float f; unsigned int u; } v; v.f = f;
  return (unsigned short)((v.u + 0x8000u) >> 16);
}
// packed pair f32->bf16x2, round-half-up: 2 v_add + 1 v_perm
static __device__ __forceinline__ unsigned pk2bf(float a, float b) {
  unsigned ua = __float_as_uint(a) + 0x8000u;
  unsigned ub = __float_as_uint(b) + 0x8000u;
  return __builtin_amdgcn_perm(ub, ua, 0x07060302);  // {hi16(b), hi16(a)}
}

static __device__ __forceinline__ void lds16(const void* g, void* l) {
  __builtin_amdgcn_global_load_lds(
      (const __attribute__((address_space(1))) unsigned int*)g,
      (__attribute__((address_space(3))) unsigned int*)l, 16, 0, 0);
}

// fences for the overlap schedule
#define LGKM0_SB()  do { asm volatile("s_waitcnt lgkmcnt(0)" ::: "memory"); \
                         __builtin_amdgcn_sched_barrier(0); } while (0)
#define VMCNT0()    asm volatile("s_waitcnt vmcnt(0)" ::: "memory")
#define BARRIER()   __builtin_amdgcn_s_barrier()
#define SB0()       __builtin_amdgcn_sched_barrier(0)

// ---------------- fused cast f32 -> bf16 (all 7 tensors, one launch) ----------
__global__ __launch_bounds__(256) void cast_all(
    const float* __restrict__ xq, const float* __restrict__ xk,
    const float* __restrict__ xv, const float* __restrict__ wq,
    const float* __restrict__ wk, const float* __restrict__ wv,
    const float* __restrict__ wp,
    unsigned short* __restrict__ Xq, unsigned short* __restrict__ Xk,
    unsigned short* __restrict__ Xv, unsigned short* __restrict__ Wq,
    unsigned short* __restrict__ Wk, unsigned short* __restrict__ Wv,
    unsigned short* __restrict__ Wp) {
  int i = blockIdx.x * 256 + threadIdx.x;
  const float* s; unsigned short* d; int off;
  if (i < 3 * X8) {
    int t = i / X8; off = i - t * X8;
    s = (t == 0) ? xq : (t == 1) ? xk : xv;
    d = (t == 0) ? Xq : (t == 1) ? Xk : Xv;
  } else {
    int j = i - 3 * X8; int t = j / W8; off = j - t * W8;
    s = (t == 0) ? wq : (t == 1) ? wk : (t == 2) ? wv : wp;
    d = (t == 0) ? Wq : (t == 1) ? Wk : (t == 2) ? Wv : Wp;
  }
  const float4* sp = (const float4*)s + (size_t)off * 2;
  float4 a = sp[0], b = sp[1];
  uint4 o;
  o.x = pk2bf(a.x, a.y); o.y = pk2bf(a.z, a.w);
  o.z = pk2bf(b.x, b.y); o.w = pk2bf(b.z, b.w);
  *(uint4*)(d + (size_t)off * 8) = o;
}

// ---------------- fused QKV NT-GEMM: r15 m97-structure 128x128 ---------------
// 576 blocks, XCD-swizzled (576 = 8*72). z=0: Q = Xq Wq^T (*QSCALE at store);
// z=1: K = Xk Wk^T; z=2: V^T = Wv Xv^T (coalesced Vt writes).
// Per block: 128x128 tile, BK=64, 4 waves each 64x64 (4x4 acc of 16x16).
// Per ks: 8 ds_read_b128 feed 16 MFMA (m97 ratio). 2-phase overlap schedule:
// frag reads -> lgkm0+schedbar+barrier -> stage(k0+64) same buffer -> MFMA
// (hides staging L2 latency) -> vmcnt0+barrier.
__global__ __launch_bounds__(256) void gemm_qkv(
    const unsigned short* __restrict__ Xq, const unsigned short* __restrict__ Xk,
    const unsigned short* __restrict__ Xv, const unsigned short* __restrict__ Wq,
    const unsigned short* __restrict__ Wk, const unsigned short* __restrict__ Wv,
    unsigned short* __restrict__ Qo, unsigned short* __restrict__ Ko,
    unsigned short* __restrict__ Vo) {
  int i0 = blockIdx.x;
  int tg = (i0 & 7) * 72 + (i0 >> 3);      // XCD swizzle: xcd owns 72 tiles
  int z = tg % 3; int u = tg / 3;          // u in [0,192)
  int xn = u % 6, y = u / 6;               // 6 n-tiles (128), 32 m-tiles (128)
  const unsigned short* A; const unsigned short* B; int am0, bn0;
  if (z == 0)      { A = Xq; B = Wq; am0 = y * 128; bn0 = xn * 128; }
  else if (z == 1) { A = Xk; B = Wk; am0 = y * 128; bn0 = xn * 128; }
  else             { A = Wv; B = Xv; am0 = xn * 128; bn0 = y * 128; }
  __shared__ __align__(16) unsigned short S[256 * 64];   // A rows 0..127, B rows 128..255
  int tid = threadIdx.x, lane = tid & 63, wave = tid >> 6;
  int quad = lane >> 4, l15 = lane & 15, l7 = l15 & 7;

  const unsigned short* gptr[8]; int ldo[8];
#pragma unroll
  for (int i = 0; i < 8; i++) {
    int idx = i * 256 + tid;
    int row = idx >> 3, c = (idx & 7) ^ (row & 7);
    gptr[i] = (row < 128 ? A + (size_t)(am0 + row) * CDIM
                         : B + (size_t)(bn0 + row - 128) * CDIM) + c * 8;
    ldo[i] = idx * 8;
  }
  floatx4 acc[16];
#pragma unroll
  for (int i = 0; i < 16; i++) acc[i] = (floatx4){0.f, 0.f, 0.f, 0.f};

  // prologue: stage k0=0
#pragma unroll
  for (int i = 0; i < 8; i++) lds16(gptr[i], &S[ldo[i]]);
  VMCNT0();
  BARRIER();

  int wm = (wave >> 1) * 64, wn = (wave & 1) * 64;
  for (int k0 = 0; k0 < CDIM; k0 += 64) {
    bf16x8 af[2][4], bfr[2][4];
#pragma unroll
    for (int ks = 0; ks < 2; ks++) {
      int csw = ((ks * 4 + quad) ^ l7) * 8;
#pragma unroll
      for (int i = 0; i < 4; i++)
        af[ks][i] = *(const bf16x8*)&S[(wm + i * 16 + l15) * 64 + csw];
#pragma unroll
      for (int j = 0; j < 4; j++)
        bfr[ks][j] = *(const bf16x8*)&S[(128 + wn + j * 16 + l15) * 64 + csw];
    }
    LGKM0_SB();
    BARRIER();
    if (k0 + 64 < CDIM) {
#pragma unroll
      for (int i = 0; i < 8; i++) lds16(gptr[i] + k0 + 64, &S[ldo[i]]);
    }
    SB0();
#pragma unroll
    for (int ks = 0; ks < 2; ks++)
#pragma unroll
      for (int mi = 0; mi < 4; mi++)
#pragma unroll
        for (int ni = 0; ni < 4; ni++)
          acc[mi * 4 + ni] = __builtin_amdgcn_mfma_f32_16x16x32_bf16(
              af[ks][mi], bfr[ks][ni], acc[mi * 4 + ni], 0, 0, 0);
    VMCNT0();
    BARRIER();
  }

  if (z < 2) {
#pragma unroll
    for (int mi = 0; mi < 4; mi++)
#pragma unroll
      for (int ni = 0; ni < 4; ni++)
#pragma unroll
        for (int r = 0; r < 4; r++) {
          int grow = am0 + wm + mi * 16 + quad * 4 + r;
          int gcol = bn0 + wn + ni * 16 + l15;
          float v = acc[mi * 4 + ni][r];
          int b = grow >> 11, nq = grow & 2047, h = gcol >> 6, dd = gcol & 63;
          if (z == 0)
            Qo[((size_t)(b * NH + h) * NSEQ + nq) * HD + dd] = f2bf(v * QSCALE);
          else
            Ko[((size_t)(b * NH + h) * NSEQ + nq) * HD + dd] = f2bf(v);
        }
  } else {
#pragma unroll
    for (int mi = 0; mi < 4; mi++)
#pragma unroll
      for (int ni = 0; ni < 4; ni++)
#pragma unroll
        for (int r = 0; r < 4; r++) {
          int o = am0 + wm + mi * 16 + quad * 4 + r;
          int mgl = bn0 + wn + ni * 16 + l15;
          int b = mgl >> 11, nq = mgl & 2047;
          Vo[((size_t)b * CDIM + o) * NSEQ + nq] = f2bf(acc[mi * 4 + ni][r]);
        }
  }
}

// ---------------- flash attention: r14 = r13 + overlap schedule --------------
// Q,K: [24][2048][64] bf16 (Q pre-scaled); Vt: [24][64][2048] bf16.
// ctx: [4096][768] bf16. 768 blocks x 256 thr = 4 waves:
//   wave = (half<<1)|qsub: qsub selects 32 q-rows, half selects kv half (1024).
// Single 8KB K + 8KB V buffer per half. Per tile: 16 frag ds_read -> lgkm0 +
// sched_barrier + s_barrier (all readers done) -> stage tile t+1 into the SAME
// buffer -> register-only compute (QK 32x32 MFMA, exp2, pack, permlane, PV)
// hides the staging L2 latency -> vmcnt0 + s_barrier (stage visible).
// P never touches LDS (r13); l = VALU tree + one permlane swap.
// Max-free softmax => halves combine exactly through LDS (swizzled Obuf).
__global__ __launch_bounds__(256, 3) void attn_kernel(
    const unsigned short* __restrict__ Q, const unsigned short* __restrict__ K,
    const unsigned short* __restrict__ Vt, unsigned short* __restrict__ ctx) {
  int i0 = blockIdx.x;
  int xcd = i0 & 7; int t0 = i0 >> 3;
  int bh = xcd * 3 + (t0 >> 5);
  int qt = t0 & 31;
  int tid = threadIdx.x, lane = tid & 63, wave = tid >> 6;
  int half = wave >> 1, qsub = wave & 1;
  int l31 = lane & 31, hi = lane >> 5;
  __shared__ __align__(16) unsigned short Ks[2][64 * 64];
  __shared__ __align__(16) unsigned short Vs[2][64 * 64];
  __shared__ float Lbuf[64];

  const unsigned short* Qg = Q + ((size_t)bh * NSEQ + qt * 64 + qsub * 32) * HD;
  const unsigned short* Kg = K + ((size_t)bh * NSEQ + half * 1024) * HD;
  const unsigned short* Vg = Vt + (size_t)bh * HD * NSEQ + half * 1024;

  // Q fragments (B-operand): lane holds Q[q=l31][d = dchunk*16 + hi*8 + j]
  bf16x8 qf[4];
#pragma unroll
  for (int dc = 0; dc < 4; dc++)
    qf[dc] = *(const bf16x8*)(Qg + l31 * HD + dc * 16 + hi * 8);

  // K/V staging: each half's 128 threads stage 8KB K + 8KB V
  int tid2 = tid & 127;
  int kgo[4], vgo[4], ldst[4];
#pragma unroll
  for (int i = 0; i < 4; i++) {
    int idx = i * 128 + tid2;
    int R = idx >> 3, c = (idx & 7) ^ (R & 7);
    kgo[i] = R * HD + c * 8;
    vgo[i] = R * NSEQ + c * 8;
    ldst[i] = idx * 8;
  }
  unsigned short* Ksh = Ks[half];
  unsigned short* Vsh = Vs[half];

  floatx16 o[2];
#pragma unroll
  for (int dt = 0; dt < 2; dt++) o[dt] = (floatx16)(0.f);
  float l_acc = 0.f;

  // prologue: stage tile 0
#pragma unroll
  for (int i = 0; i < 4; i++) {
    lds16(Kg + kgo[i], &Ksh[ldst[i]]);
    lds16(Vg + vgo[i], &Vsh[ldst[i]]);
  }
  VMCNT0();
  BARRIER();

  for (int t = 0; t < 16; t++) {
    // (a) fragment reads of tile t
    bf16x8 kf[2][4];
#pragma unroll
    for (int kb = 0; kb < 2; kb++)
#pragma unroll
      for (int dc = 0; dc < 4; dc++) {
        int R = kb * 32 + l31, c = dc * 2 + hi;
        kf[kb][dc] = *(const bf16x8*)&Ksh[R * 64 + ((c ^ (R & 7)) * 8)];
      }
    bf16x8 vf[2][4];
#pragma unroll
    for (int dt = 0; dt < 2; dt++)
#pragma unroll
      for (int j = 0; j < 4; j++) {
        int R = dt * 32 + l31, c = j * 2 + hi;
        vf[dt][j] = *(const bf16x8*)&Vsh[R * 64 + ((c ^ (R & 7)) * 8)];
      }
    // (b) readers-done fence
    LGKM0_SB();
    BARRIER();
    // (c) stage tile t+1 into the same buffer (in flight across compute)
    if (t < 15) {
      int k0n = (t + 1) * 64;
#pragma unroll
      for (int i = 0; i < 4; i++) {
        lds16(Kg + (size_t)k0n * HD + kgo[i], &Ksh[ldst[i]]);
        lds16(Vg + k0n + vgo[i], &Vsh[ldst[i]]);
      }
    }
    SB0();
    // (d) register-only compute
#pragma unroll
    for (int kb = 0; kb < 2; kb++) {
      floatx16 st = (floatx16)(0.f);
#pragma unroll
      for (int dc = 0; dc < 4; dc++)
        st = __builtin_amdgcn_mfma_f32_32x32x16_bf16(kf[kb][dc], qf[dc], st, 0, 0, 0);
      // exp2 all 16 scores (max-free softmax)
      float p[16];
#pragma unroll
      for (int r = 0; r < 16; r++) p[r] = __builtin_exp2f(st[r]);
      // l: VALU tree sum of this lane's 16 values
      l_acc += ((p[0] + p[1]) + (p[2] + p[3])) + ((p[4] + p[5]) + (p[6] + p[7])) +
               (((p[8] + p[9]) + (p[10] + p[11])) + ((p[12] + p[13]) + (p[14] + p[15])));
      // pack pairs: w[i] = bf16{p[2i], p[2i+1]}
      unsigned w[8];
#pragma unroll
      for (int i = 0; i < 8; i++) w[i] = pk2bf(p[2 * i], p[2 * i + 1]);
      // permlane32_swap: build PV B-fragments (k = hi*8 + j within each kv16)
#pragma unroll
      for (int kvs = 0; kvs < 2; kvs++) {
        unsigned a0 = w[kvs * 4 + 0], b0 = w[kvs * 4 + 2];
        unsigned a1 = w[kvs * 4 + 1], b1 = w[kvs * 4 + 3];
        asm volatile("v_permlane32_swap_b32 %0, %1" : "+v"(a0), "+v"(b0));
        asm volatile("v_permlane32_swap_b32 %0, %1" : "+v"(a1), "+v"(b1));
        uintx4 pw; pw[0] = a0; pw[1] = a1; pw[2] = b0; pw[3] = b1;
        bf16x8 pb = *(bf16x8*)&pw;
#pragma unroll
        for (int dt = 0; dt < 2; dt++)
          o[dt] = __builtin_amdgcn_mfma_f32_32x32x16_bf16(
              vf[dt][kb * 2 + kvs], pb, o[dt], 0, 0, 0);
      }
    }
    // (e) stage-done fence (cheap: issued ~400 cyc ago)
    VMCNT0();
    BARRIER();
  }

  // complete l across lane halves: one permlane swap + add
  unsigned lu = __float_as_uint(l_acc), lv = __float_as_uint(l_acc);
  asm volatile("v_permlane32_swap_b32 %0, %1" : "+v"(lu), "+v"(lv));
  float lfull = __uint_as_float(lu) + __uint_as_float(lv);

  // in-block kv-half combine: half-1 -> LDS, half-0 adds + stores.
  // Obuf chunks XOR-swizzled by q (linear [64q][64d] f32 would be 32-way).
  float* Obuf = (float*)&Ks[0][0];   // 64q x 64d f32 = 16 KB (== Ks)
  int q = qsub * 32 + l31;
  if (half == 1) {
#pragma unroll
    for (int dt = 0; dt < 2; dt++)
#pragma unroll
      for (int rq = 0; rq < 4; rq++) {
        int ch = (dt * 8 + rq * 2 + hi) ^ (l31 & 15);
        floatx4 v4 = {o[dt][rq * 4 + 0], o[dt][rq * 4 + 1],
                      o[dt][rq * 4 + 2], o[dt][rq * 4 + 3]};
        *(floatx4*)&Obuf[q * 64 + ch * 4] = v4;
      }
    if (lane < 32) Lbuf[qsub * 32 + lane] = lfull;
  }
  __syncthreads();
  if (half == 0) {
    int b = bh / NH, h = bh - b * NH;
    float inv = 1.f / (lfull + Lbuf[q]);
    int qrow = qt * 64 + q;
#pragma unroll
    for (int dt = 0; dt < 2; dt++)
#pragma unroll
      for (int rq = 0; rq < 4; rq++) {
        int ch = (dt * 8 + rq * 2 + hi) ^ (l31 & 15);
        floatx4 ob = *(floatx4*)&Obuf[q * 64 + ch * 4];
        float v0 = (o[dt][rq * 4 + 0] + ob[0]) * inv;
        float v1 = (o[dt][rq * 4 + 1] + ob[1]) * inv;
        float v2 = (o[dt][rq * 4 + 2] + ob[2]) * inv;
        float v3 = (o[dt][rq * 4 + 3] + ob[3]) * inv;
        size_t gbase = (size_t)(b * NSEQ + qrow) * CDIM + h * HD +
                       dt * 32 + rq * 8 + hi * 4;
        *(uint2*)&ctx[gbase] = make_uint2(pk2bf(v0, v1), pk2bf(v2, v3));
      }
  }
}

// ------------- output NT-GEMM + bias, 64x96 tiles, BK=128, XCD-swizzled ------
// r14: 2-phase overlap schedule.
__global__ __launch_bounds__(256) void gemm_out(
    const unsigned short* __restrict__ A, const unsigned short* __restrict__ B,
    const float* __restrict__ bias, float* __restrict__ out) {
  int i0 = blockIdx.x;                  // 512 blocks = 2/CU
  int mg = i0 & 7; int t0 = i0 >> 3;    // t0 in [0,64)
  int n0 = (t0 & 7) * 96;
  int m0 = (mg * 8 + (t0 >> 3)) * 64;
  __shared__ __align__(16) unsigned short S[160 * 128];  // A rows 0..63, B rows 64..159
  int tid = threadIdx.x, lane = tid & 63, wave = tid >> 6;
  int quad = lane >> 4, l15 = lane & 15, l7 = l15 & 7;
  int wm = (wave >> 1) * 32, wn = (wave & 1) * 48;
  floatx4 acc[6];
#pragma unroll
  for (int i = 0; i < 6; i++) acc[i] = (floatx4){0.f, 0.f, 0.f, 0.f};

  int sro[10]; const unsigned short* sgp[10];
#pragma unroll
  for (int i = 0; i < 10; i++) {       // 160 rows x 16 chunks = 2560 = 10*256
    int idx = i * 256 + tid;
    int R = idx >> 4, c4 = idx & 15;
    int cs = (c4 & 8) | ((c4 & 7) ^ (R & 7));
    sgp[i] = ((R < 64) ? A + (size_t)(m0 + R) * CDIM
                       : B + (size_t)(n0 + R - 64) * CDIM) + cs * 8;
    sro[i] = idx * 8;
  }
  // prologue: stage k0=0
#pragma unroll
  for (int i = 0; i < 10; i++) lds16(sgp[i], &S[sro[i]]);
  VMCNT0();
  BARRIER();

  for (int k0 = 0; k0 < CDIM; k0 += 128) {
    bf16x8 af[4][2], bfr[4][3];
#pragma unroll
    for (int ks = 0; ks < 4; ks++) {
      int c = ks * 4 + quad;
      int csw = ((c & 8) | ((c & 7) ^ l7)) * 8;
#pragma unroll
      for (int i = 0; i < 2; i++)
        af[ks][i] = *(const bf16x8*)&S[(wm + i * 16 + l15) * 128 + csw];
#pragma unroll
      for (int j = 0; j < 3; j++)
        bfr[ks][j] = *(const bf16x8*)&S[(64 + wn + j * 16 + l15) * 128 + csw];
    }
    LGKM0_SB();
    BARRIER();
    if (k0 + 128 < CDIM) {
#pragma unroll
      for (int i = 0; i < 10; i++) lds16(sgp[i] + k0 + 128, &S[sro[i]]);
    }
    SB0();
#pragma unroll
    for (int ks = 0; ks < 4; ks++)
#pragma unroll
      for (int mi = 0; mi < 2; mi++)
#pragma unroll
        for (int ni = 0; ni < 3; ni++)
          acc[mi * 3 + ni] = __builtin_amdgcn_mfma_f32_16x16x32_bf16(
              af[ks][mi], bfr[ks][ni], acc[mi * 3 + ni], 0, 0, 0);
    VMCNT0();
    BARRIER();
  }
  float bv[3];
#pragma unroll
  for (int ni = 0; ni < 3; ni++) bv[ni] = bias[n0 + wn + ni * 16 + l15];
#pragma unroll
  for (int mi = 0; mi < 2; mi++)
#pragma unroll
    for (int ni = 0; ni < 3; ni++)
#pragma unroll
      for (int r = 0; r < 4; r++) {
        int grow = m0 + wm + mi * 16 + quad * 4 + r;
        int gcol = n0 + wn + ni * 16 + l15;
        out[(size_t)grow * CDIM + gcol] = acc[mi * 3 + ni][r] + bv[ni];
      }
}

extern "C" void kernel_launch(void* const* d_in, const int* in_sizes, int n_in,
                              void* d_out, int out_size, void* d_ws, size_t ws_size,
                              hipStream_t stream) {
  const float* xq = (const float*)d_in[0];
  const float* xk = (const float*)d_in[1];
  const float* xv = (const float*)d_in[2];
  const float* wq = (const float*)d_in[3];
  const float* wk = (const float*)d_in[4];
  const float* wv = (const float*)d_in[5];
  const float* wp = (const float*)d_in[6];
  const float* bp = (const float*)d_in[7];
  float* out = (float*)d_out;

  char* p = (char*)d_ws;
  unsigned short* Xq = (unsigned short*)p; p += (size_t)XEL * 2;
  unsigned short* Xk = (unsigned short*)p; p += (size_t)XEL * 2;
  unsigned short* Xv = (unsigned short*)p; p += (size_t)XEL * 2;
  unsigned short* Wq = (unsigned short*)p; p += (size_t)WEL * 2;
  unsigned short* Wk = (unsigned short*)p; p += (size_t)WEL * 2;
  unsigned short* Wv = (unsigned short*)p; p += (size_t)WEL * 2;
  unsigned short* Wp = (unsigned short*)p; p += (size_t)WEL * 2;
  unsigned short* Qb = (unsigned short*)p; p += (size_t)XEL * 2;
  unsigned short* Kb = (unsigned short*)p; p += (size_t)XEL * 2;
  unsigned short* Vb = (unsigned short*)p; p += (size_t)XEL * 2;
  unsigned short* Cx = (unsigned short*)p; p += (size_t)XEL * 2;

  cast_all<<<(3 * X8 + 4 * W8) / 256, 256, 0, stream>>>(
      xq, xk, xv, wq, wk, wv, wp, Xq, Xk, Xv, Wq, Wk, Wv, Wp);

  gemm_qkv<<<576, 256, 0, stream>>>(
      Xq, Xk, Xv, Wq, Wk, Wv, Qb, Kb, Vb);

  attn_kernel<<<768, 256, 0, stream>>>(Qb, Kb, Vb, Cx);

  gemm_out<<<512, 256, 0, stream>>>(Cx, Wp, bp, out);
}

// Round 9
// 177.703 us; speedup vs baseline: 1.0159x; 1.0159x over previous
//
#include <hip/hip_runtime.h>
#include <hip/hip_bf16.h>

// Attention: xq/xk/xv [2,2048,768] f32, W* [768,768] f32 ([out,in]), bp [768] f32.
// Pipeline: fused cast->bf16, fused QKV NT-GEMM (r14 version: 128x96 tiles,
// 768 blocks = 3/CU balanced, 2-phase overlap schedule; scale*log2e folded
// into Q; V computed TRANSPOSED via swapped operands), flash attention
// (r16b structure: WAVE-PRIVATE kv-quarters -- each wave owns 512 kv, stages
// its own 32x64 K / 64x32 V tiles into private LDS, ZERO barriers in the
// 16-tile main loop (wave-local lgkm/vmcnt waits only); 32x32 MFMA,
// in-register P via permlane32_swap; barrier after loop (Ob aliases K/V LDS)
// then 3-barrier tree-combine epilogue),
// output NT-GEMM + bias (64x96 tiles, BK=128, overlap schedule).

#define NSEQ 2048
#define CDIM 768
#define NH   12
#define HD   64
#define MTOT 4096            // B*NSEQ
#define XEL  (MTOT*CDIM)     // 3145728
#define WEL  (CDIM*CDIM)     // 589824
#define X8   (XEL/8)         // 393216
#define W8   (WEL/8)         // 73728
#define QSCALE 0.18033688011112042f   // 0.125 * log2(e); scores consumed by exp2

typedef __attribute__((ext_vector_type(8))) short bf16x8;
typedef __attribute__((ext_vector_type(4))) float floatx4;
typedef __attribute__((ext_vector_type(16))) float floatx16;
typedef __attribute__((ext_vector_type(4))) unsigned int uintx4;

// scalar f32->bf16, round-half-up (2 VALU)
static __device__ __forceinline__ unsigned short f2bf(float f) {
  union { float f; unsigned int u; } v; v.f = f;
  return (unsigned short)((v.u + 0x8000u) >> 16);
}
// packed pair f32->bf16x2, round-half-up: 2 v_add + 1 v_perm
static __device__ __forceinline__ unsigned pk2bf(float a, float b) {
  unsigned ua = __float_as_uint(a) + 0x8000u;
  unsigned ub = __float_as_uint(b) + 0x8000u;
  return __builtin_amdgcn_perm(ub, ua, 0x07060302);  // {hi16(b), hi16(a)}
}

static __device__ __forceinline__ void lds16(const void* g, void* l) {
  __builtin_amdgcn_global_load_lds(
      (const __attribute__((address_space(1))) unsigned int*)g,
      (__attribute__((address_space(3))) unsigned int*)l, 16, 0, 0);
}

// fences for the overlap schedules
#define LGKM0_SB()  do { asm volatile("s_waitcnt lgkmcnt(0)" ::: "memory"); \
                         __builtin_amdgcn_sched_barrier(0); } while (0)
#define VMCNT0()    asm volatile("s_waitcnt vmcnt(0)" ::: "memory")
#define BARRIER()   __builtin_amdgcn_s_barrier()
#define SB0()       __builtin_amdgcn_sched_barrier(0)

// ---------------- fused cast f32 -> bf16 (all 7 tensors, one launch) ----------
__global__ __launch_bounds__(256) void cast_all(
    const float* __restrict__ xq, const float* __restrict__ xk,
    const float* __restrict__ xv, const float* __restrict__ wq,
    const float* __restrict__ wk, const float* __restrict__ wv,
    const float* __restrict__ wp,
    unsigned short* __restrict__ Xq, unsigned short* __restrict__ Xk,
    unsigned short* __restrict__ Xv, unsigned short* __restrict__ Wq,
    unsigned short* __restrict__ Wk, unsigned short* __restrict__ Wv,
    unsigned short* __restrict__ Wp) {
  int i = blockIdx.x * 256 + threadIdx.x;
  const float* s; unsigned short* d; int off;
  if (i < 3 * X8) {
    int t = i / X8; off = i - t * X8;
    s = (t == 0) ? xq : (t == 1) ? xk : xv;
    d = (t == 0) ? Xq : (t == 1) ? Xk : Xv;
  } else {
    int j = i - 3 * X8; int t = j / W8; off = j - t * W8;
    s = (t == 0) ? wq : (t == 1) ? wk : (t == 2) ? wv : wp;
    d = (t == 0) ? Wq : (t == 1) ? Wk : (t == 2) ? Wv : Wp;
  }
  const float4* sp = (const float4*)s + (size_t)off * 2;
  float4 a = sp[0], b = sp[1];
  uint4 o;
  o.x = pk2bf(a.x, a.y); o.y = pk2bf(a.z, a.w);
  o.z = pk2bf(b.x, b.y); o.w = pk2bf(b.z, b.w);
  *(uint4*)(d + (size_t)off * 8) = o;
}

// ---------------- fused QKV NT-GEMM: r14 version (768 blocks, 3/CU) ---------
// z=0: Q = Xq Wq^T * QSCALE, tile 128m x 96n ; z=1: K; z=2: V^T = Wv Xv^T.
// 2-phase overlap: frag reads -> lgkm0+schedbar+barrier -> stage(k0+64) same
// buffer -> MFMA (hides staging latency) -> vmcnt0+barrier.
__global__ __launch_bounds__(256) void gemm_qkv(
    const unsigned short* __restrict__ Xq, const unsigned short* __restrict__ Xk,
    const unsigned short* __restrict__ Xv, const unsigned short* __restrict__ Wq,
    const unsigned short* __restrict__ Wk, const unsigned short* __restrict__ Wv,
    unsigned short* __restrict__ Qo, unsigned short* __restrict__ Ko,
    unsigned short* __restrict__ Vo) {
  int i0 = blockIdx.x;
  int mg = i0 & 7; int t0 = i0 >> 3;       // t0 in [0,96)
  int z = t0 % 3; int u = t0 / 3;          // u in [0,32)
  int xn = u & 7, ysub = u >> 3;           // 8 n-tiles x 4 m-subtiles
  int y = mg * 4 + ysub;                   // m-tile in [0,32)
  const unsigned short* A; const unsigned short* B; int am0, bn0, RA;
  if (z == 0)      { A = Xq; B = Wq; am0 = y * 128; bn0 = xn * 96; RA = 128; }
  else if (z == 1) { A = Xk; B = Wk; am0 = y * 128; bn0 = xn * 96; RA = 128; }
  else             { A = Wv; B = Xv; am0 = xn * 96; bn0 = y * 128; RA = 96; }
  __shared__ __align__(16) unsigned short S[224 * 64];
  int tid = threadIdx.x, lane = tid & 63, wave = tid >> 6;
  int quad = lane >> 4, l15 = lane & 15, l7 = l15 & 7;

  const unsigned short* gptr[7]; int ldo[7];
#pragma unroll
  for (int i = 0; i < 7; i++) {
    int idx = i * 256 + tid;
    int row = idx >> 3, c = (idx & 7) ^ (row & 7);
    gptr[i] = (row < RA ? A + (size_t)(am0 + row) * CDIM
                        : B + (size_t)(bn0 + row - RA) * CDIM) + c * 8;
    ldo[i] = idx * 8;
  }
  floatx4 acc[12];
#pragma unroll
  for (int i = 0; i < 12; i++) acc[i] = (floatx4){0.f, 0.f, 0.f, 0.f};

  // prologue: stage k0=0
#pragma unroll
  for (int i = 0; i < 7; i++) lds16(gptr[i], &S[ldo[i]]);
  VMCNT0();
  BARRIER();

  if (z < 2) {
    int wm = (wave >> 1) * 64, wn = (wave & 1) * 48;
    for (int k0 = 0; k0 < CDIM; k0 += 64) {
      bf16x8 af[2][4], bfr[2][3];
#pragma unroll
      for (int ks = 0; ks < 2; ks++) {
        int csw = ((ks * 4 + quad) ^ l7) * 8;
#pragma unroll
        for (int i = 0; i < 4; i++)
          af[ks][i] = *(const bf16x8*)&S[(wm + i * 16 + l15) * 64 + csw];
#pragma unroll
        for (int j = 0; j < 3; j++)
          bfr[ks][j] = *(const bf16x8*)&S[(128 + wn + j * 16 + l15) * 64 + csw];
      }
      LGKM0_SB();
      BARRIER();
      if (k0 + 64 < CDIM) {
#pragma unroll
        for (int i = 0; i < 7; i++) lds16(gptr[i] + k0 + 64, &S[ldo[i]]);
      }
      SB0();
#pragma unroll
      for (int ks = 0; ks < 2; ks++)
#pragma unroll
        for (int mi = 0; mi < 4; mi++)
#pragma unroll
          for (int ni = 0; ni < 3; ni++)
            acc[mi * 3 + ni] = __builtin_amdgcn_mfma_f32_16x16x32_bf16(
                af[ks][mi], bfr[ks][ni], acc[mi * 3 + ni], 0, 0, 0);
      VMCNT0();
      BARRIER();
    }
#pragma unroll
    for (int mi = 0; mi < 4; mi++)
#pragma unroll
      for (int ni = 0; ni < 3; ni++)
#pragma unroll
        for (int r = 0; r < 4; r++) {
          int grow = am0 + wm + mi * 16 + quad * 4 + r;
          int gcol = bn0 + wn + ni * 16 + l15;
          float v = acc[mi * 3 + ni][r];
          int b = grow >> 11, nq = grow & 2047, h = gcol >> 6, dd = gcol & 63;
          if (z == 0)
            Qo[((size_t)(b * NH + h) * NSEQ + nq) * HD + dd] = f2bf(v * QSCALE);
          else
            Ko[((size_t)(b * NH + h) * NSEQ + nq) * HD + dd] = f2bf(v);
        }
  } else {
    int wm = (wave & 1) * 48, wn = (wave >> 1) * 64;
    for (int k0 = 0; k0 < CDIM; k0 += 64) {
      bf16x8 af[2][3], bfr[2][4];
#pragma unroll
      for (int ks = 0; ks < 2; ks++) {
        int csw = ((ks * 4 + quad) ^ l7) * 8;
#pragma unroll
        for (int i = 0; i < 3; i++)
          af[ks][i] = *(const bf16x8*)&S[(wm + i * 16 + l15) * 64 + csw];
#pragma unroll
        for (int j = 0; j < 4; j++)
          bfr[ks][j] = *(const bf16x8*)&S[(96 + wn + j * 16 + l15) * 64 + csw];
      }
      LGKM0_SB();
      BARRIER();
      if (k0 + 64 < CDIM) {
#pragma unroll
        for (int i = 0; i < 7; i++) lds16(gptr[i] + k0 + 64, &S[ldo[i]]);
      }
      SB0();
#pragma unroll
      for (int ks = 0; ks < 2; ks++)
#pragma unroll
        for (int mi = 0; mi < 3; mi++)
#pragma unroll
          for (int ni = 0; ni < 4; ni++)
            acc[mi * 4 + ni] = __builtin_amdgcn_mfma_f32_16x16x32_bf16(
                af[ks][mi], bfr[ks][ni], acc[mi * 4 + ni], 0, 0, 0);
      VMCNT0();
      BARRIER();
    }
#pragma unroll
    for (int mi = 0; mi < 3; mi++)
#pragma unroll
      for (int ni = 0; ni < 4; ni++)
#pragma unroll
        for (int r = 0; r < 4; r++) {
          int o = am0 + wm + mi * 16 + quad * 4 + r;
          int mgl = bn0 + wn + ni * 16 + l15;
          int b = mgl >> 11, nq = mgl & 2047;
          Vo[((size_t)b * CDIM + o) * NSEQ + nq] = f2bf(acc[mi * 4 + ni][r]);
        }
  }
}

// ---------------- flash attention: r16b wave-private kv-quarters -------------
// Q,K: [24][2048][64] bf16 (Q pre-scaled); Vt: [24][64][2048] bf16.
// ctx: [4096][768] bf16. 768 blocks x 256 thr = 4 waves; block = 64 q x 2048 kv.
// Each wave owns kv range [wave*512, wave*512+512) for ALL 64 q (2 qi of 32):
// stages its own 32x64 K-tile (4KB) + 64x32 V-tile (4KB) into PRIVATE LDS --
// the 16-tile main loop has ZERO barriers; waves slip freely. Per tile:
// 8 ds_read -> lgkm0 (own reads drained) -> 8 global_load_lds(t+1, same buf)
// -> register compute (8 QK + 8 PV 32x32 MFMA, 32 exp2, in-reg P repack via
// permlane32_swap) -> vmcnt0 (own stage landed). Max-free softmax; l = VALU
// tree + permlane. Epilogue: __syncthreads (Ob aliases all waves' K/V tiles!)
// then tree combine (waves 2,3 -> LDS; 0,1 add; 1 -> LDS; 0 adds + stores).
// XCD-swizzled: blk%8 owns 3 heads.
__global__ __launch_bounds__(256, 2) void attn_kernel(
    const unsigned short* __restrict__ Q, const unsigned short* __restrict__ K,
    const unsigned short* __restrict__ Vt, unsigned short* __restrict__ ctx) {
  int i0 = blockIdx.x;
  int xcd = i0 & 7; int t0 = i0 >> 3;
  int bh = xcd * 3 + (t0 >> 5);
  int qt = t0 & 31;
  int tid = threadIdx.x, lane = tid & 63, wave = tid >> 6;
  int l31 = lane & 31, hi = lane >> 5;
  // 32KB: [0,8191] = 4 waves' K tiles (32x64), [8192,16383] = 4 waves' V (64x32)
  __shared__ __align__(16) unsigned short SM[16384];
  __shared__ float Lb[3][2][32];

  const unsigned short* Qg = Q + ((size_t)bh * NSEQ + qt * 64) * HD;
  const unsigned short* Kg = K + ((size_t)bh * NSEQ + wave * 512) * HD;
  const unsigned short* Vg = Vt + (size_t)bh * HD * NSEQ + wave * 512;
  unsigned short* Ksh = &SM[wave * 2048];
  unsigned short* Vsh = &SM[8192 + wave * 2048];

  // Q fragments (B-operand): qf[qi][dc] = Q[q=qi*32+l31][dc*16 + hi*8 .. +8]
  bf16x8 qf[2][4];
#pragma unroll
  for (int qi = 0; qi < 2; qi++)
#pragma unroll
    for (int dc = 0; dc < 4; dc++)
      qf[qi][dc] = *(const bf16x8*)(Qg + (qi * 32 + l31) * HD + dc * 16 + hi * 8);

  // staging offsets (wave = 64 lanes stages its own tiles)
  // K tile 32 rows x 64 cols: 8 chunks/row; V tile 64 rows x 32 cols: 4/row
  int kgo[4], kst[4], vgo[4], vst[4];
#pragma unroll
  for (int i = 0; i < 4; i++) {
    int idx = i * 64 + lane;
    int Rk = idx >> 3, ck = (idx & 7) ^ (Rk & 7);
    kgo[i] = Rk * HD + ck * 8; kst[i] = idx * 8;
    int Rv = idx >> 2, cv = (idx & 3) ^ (Rv & 3);
    vgo[i] = Rv * NSEQ + cv * 8; vst[i] = idx * 8;
  }

  floatx16 o[2][2];
#pragma unroll
  for (int qi = 0; qi < 2; qi++)
#pragma unroll
    for (int dt = 0; dt < 2; dt++) o[qi][dt] = (floatx16)(0.f);
  float l_acc[2] = {0.f, 0.f};

  // prologue: stage tile 0 (wave-private; no barrier, just own vmcnt)
#pragma unroll
  for (int i = 0; i < 4; i++) {
    lds16(Kg + kgo[i], &Ksh[kst[i]]);
    lds16(Vg + vgo[i], &Vsh[vst[i]]);
  }
  VMCNT0();
  SB0();

  for (int t = 0; t < 16; t++) {
    // (a) fragment reads of tile t (wave-private LDS)
    bf16x8 kf[4];
#pragma unroll
    for (int dc = 0; dc < 4; dc++) {
      int c = dc * 2 + hi;
      kf[dc] = *(const bf16x8*)&Ksh[l31 * 64 + ((c ^ (l31 & 7)) * 8)];
    }
    bf16x8 vf[2][2];
#pragma unroll
    for (int dt = 0; dt < 2; dt++)
#pragma unroll
      for (int kvs = 0; kvs < 2; kvs++) {
        int R = dt * 32 + l31, c = kvs * 2 + hi;
        vf[dt][kvs] = *(const bf16x8*)&Vsh[R * 32 + ((c ^ (R & 3)) * 8)];
      }
    // (b) own reads drained -> safe to overwrite own buffer
    LGKM0_SB();
    if (t < 15) {
      int off = (t + 1) * 32;
#pragma unroll
      for (int i = 0; i < 4; i++) {
        lds16(Kg + (size_t)off * HD + kgo[i], &Ksh[kst[i]]);
        lds16(Vg + off + vgo[i], &Vsh[vst[i]]);
      }
    }
    SB0();
    // (c) register-only compute (32 kv x 64 q)
#pragma unroll
    for (int qi = 0; qi < 2; qi++) {
      floatx16 st = (floatx16)(0.f);
#pragma unroll
      for (int dc = 0; dc < 4; dc++)
        st = __builtin_amdgcn_mfma_f32_32x32x16_bf16(kf[dc], qf[qi][dc], st, 0, 0, 0);
      float p[16];
#pragma unroll
      for (int r = 0; r < 16; r++) p[r] = __builtin_exp2f(st[r]);
      l_acc[qi] += ((p[0] + p[1]) + (p[2] + p[3])) + ((p[4] + p[5]) + (p[6] + p[7])) +
                   (((p[8] + p[9]) + (p[10] + p[11])) + ((p[12] + p[13]) + (p[14] + p[15])));
      unsigned w[8];
#pragma unroll
      for (int i = 0; i < 8; i++) w[i] = pk2bf(p[2 * i], p[2 * i + 1]);
#pragma unroll
      for (int kvs = 0; kvs < 2; kvs++) {
        unsigned a0 = w[kvs * 4 + 0], b0 = w[kvs * 4 + 2];
        unsigned a1 = w[kvs * 4 + 1], b1 = w[kvs * 4 + 3];
        asm volatile("v_permlane32_swap_b32 %0, %1" : "+v"(a0), "+v"(b0));
        asm volatile("v_permlane32_swap_b32 %0, %1" : "+v"(a1), "+v"(b1));
        uintx4 pw; pw[0] = a0; pw[1] = a1; pw[2] = b0; pw[3] = b1;
        bf16x8 pb = *(bf16x8*)&pw;
#pragma unroll
        for (int dt = 0; dt < 2; dt++)
          o[qi][dt] = __builtin_amdgcn_mfma_f32_32x32x16_bf16(
              vf[dt][kvs], pb, o[qi][dt], 0, 0, 0);
      }
    }
    // (d) own stage landed (issued before compute; cheap now)
    VMCNT0();
    SB0();
  }

  // finish l across lane halves (both halves end with the full quarter-sum)
  float lf[2];
#pragma unroll
  for (int qi = 0; qi < 2; qi++) {
    unsigned lu = __float_as_uint(l_acc[qi]), lv = __float_as_uint(l_acc[qi]);
    asm volatile("v_permlane32_swap_b32 %0, %1" : "+v"(lu), "+v"(lv));
    lf[qi] = __uint_as_float(lu) + __uint_as_float(lv);
  }

  // CRITICAL: Ob aliases all waves' K/V tiles -- every wave must be out of its
  // main loop before anyone writes the combine buffer.
  __syncthreads();

  // tree combine across the 4 kv-quarter waves. Ob slot = 64q x 64d f32 (16KB).
  float* Ob = (float*)&SM[0];
  if (wave >= 2) {
    int sl = (wave - 2) * 4096;
#pragma unroll
    for (int qi = 0; qi < 2; qi++) {
      int q = qi * 32 + l31;
#pragma unroll
      for (int dt = 0; dt < 2; dt++)
#pragma unroll
        for (int rq = 0; rq < 4; rq++) {
          int ch = (dt * 8 + rq * 2 + hi) ^ (l31 & 15);
          floatx4 v4 = {o[qi][dt][rq * 4 + 0], o[qi][dt][rq * 4 + 1],
                        o[qi][dt][rq * 4 + 2], o[qi][dt][rq * 4 + 3]};
          *(floatx4*)&Ob[sl + q * 64 + ch * 4] = v4;
        }
      if (hi == 0) Lb[wave - 1][qi][l31] = lf[qi];
    }
  }
  __syncthreads();
  if (wave < 2) {
#pragma unroll
    for (int qi = 0; qi < 2; qi++) {
      int q = qi * 32 + l31;
#pragma unroll
      for (int dt = 0; dt < 2; dt++)
#pragma unroll
        for (int rq = 0; rq < 4; rq++) {
          int ch = (dt * 8 + rq * 2 + hi) ^ (l31 & 15);
          floatx4 ob = *(floatx4*)&Ob[wave * 4096 + q * 64 + ch * 4];
#pragma unroll
          for (int j = 0; j < 4; j++) o[qi][dt][rq * 4 + j] += ob[j];
        }
      lf[qi] += Lb[wave + 1][qi][l31];
    }
  }
  __syncthreads();
  if (wave == 1) {
#pragma unroll
    for (int qi = 0; qi < 2; qi++) {
      int q = qi * 32 + l31;
#pragma unroll
      for (int dt = 0; dt < 2; dt++)
#pragma unroll
        for (int rq = 0; rq < 4; rq++) {
          int ch = (dt * 8 + rq * 2 + hi) ^ (l31 & 15);
          floatx4 v4 = {o[qi][dt][rq * 4 + 0], o[qi][dt][rq * 4 + 1],
                        o[qi][dt][rq * 4 + 2], o[qi][dt][rq * 4 + 3]};
          *(floatx4*)&Ob[q * 64 + ch * 4] = v4;
        }
      if (hi == 0) Lb[0][qi][l31] = lf[qi];
    }
  }
  __syncthreads();
  if (wave == 0) {
    int b = bh / NH, h = bh - b * NH;
#pragma unroll
    for (int qi = 0; qi < 2; qi++) {
      int q = qi * 32 + l31;
      float inv = 1.f / (lf[qi] + Lb[0][qi][l31]);
      int qrow = qt * 64 + q;
#pragma unroll
      for (int dt = 0; dt < 2; dt++)
#pragma unroll
        for (int rq = 0; rq < 4; rq++) {
          int ch = (dt * 8 + rq * 2 + hi) ^ (l31 & 15);
          floatx4 ob = *(floatx4*)&Ob[q * 64 + ch * 4];
          float v0 = (o[qi][dt][rq * 4 + 0] + ob[0]) * inv;
          float v1 = (o[qi][dt][rq * 4 + 1] + ob[1]) * inv;
          float v2 = (o[qi][dt][rq * 4 + 2] + ob[2]) * inv;
          float v3 = (o[qi][dt][rq * 4 + 3] + ob[3]) * inv;
          size_t gbase = (size_t)(b * NSEQ + qrow) * CDIM + h * HD +
                         dt * 32 + rq * 8 + hi * 4;
          *(uint2*)&ctx[gbase] = make_uint2(pk2bf(v0, v1), pk2bf(v2, v3));
        }
    }
  }
}

// ------------- output NT-GEMM + bias, 64x96 tiles, BK=128, XCD-swizzled ------
// 2-phase overlap schedule.
__global__ __launch_bounds__(256) void gemm_out(
    const unsigned short* __restrict__ A, const unsigned short* __restrict__ B,
    const float* __restrict__ bias, float* __restrict__ out) {
  int i0 = blockIdx.x;                  // 512 blocks = 2/CU
  int mg = i0 & 7; int t0 = i0 >> 3;    // t0 in [0,64)
  int n0 = (t0 & 7) * 96;
  int m0 = (mg * 8 + (t0 >> 3)) * 64;
  __shared__ __align__(16) unsigned short S[160 * 128];  // A rows 0..63, B rows 64..159
  int tid = threadIdx.x, lane = tid & 63, wave = tid >> 6;
  int quad = lane >> 4, l15 = lane & 15, l7 = l15 & 7;
  int wm = (wave >> 1) * 32, wn = (wave & 1) * 48;
  floatx4 acc[6];
#pragma unroll
  for (int i = 0; i < 6; i++) acc[i] = (floatx4){0.f, 0.f, 0.f, 0.f};

  int sro[10]; const unsigned short* sgp[10];
#pragma unroll
  for (int i = 0; i < 10; i++) {       // 160 rows x 16 chunks = 2560 = 10*256
    int idx = i * 256 + tid;
    int R = idx >> 4, c4 = idx & 15;
    int cs = (c4 & 8) | ((c4 & 7) ^ (R & 7));
    sgp[i] = ((R < 64) ? A + (size_t)(m0 + R) * CDIM
                       : B + (size_t)(n0 + R - 64) * CDIM) + cs * 8;
    sro[i] = idx * 8;
  }
  // prologue: stage k0=0
#pragma unroll
  for (int i = 0; i < 10; i++) lds16(sgp[i], &S[sro[i]]);
  VMCNT0();
  BARRIER();

  for (int k0 = 0; k0 < CDIM; k0 += 128) {
    bf16x8 af[4][2], bfr[4][3];
#pragma unroll
    for (int ks = 0; ks < 4; ks++) {
      int c = ks * 4 + quad;
      int csw = ((c & 8) | ((c & 7) ^ l7)) * 8;
#pragma unroll
      for (int i = 0; i < 2; i++)
        af[ks][i] = *(const bf16x8*)&S[(wm + i * 16 + l15) * 128 + csw];
#pragma unroll
      for (int j = 0; j < 3; j++)
        bfr[ks][j] = *(const bf16x8*)&S[(64 + wn + j * 16 + l15) * 128 + csw];
    }
    LGKM0_SB();
    BARRIER();
    if (k0 + 128 < CDIM) {
#pragma unroll
      for (int i = 0; i < 10; i++) lds16(sgp[i] + k0 + 128, &S[sro[i]]);
    }
    SB0();
#pragma unroll
    for (int ks = 0; ks < 4; ks++)
#pragma unroll
      for (int mi = 0; mi < 2; mi++)
#pragma unroll
        for (int ni = 0; ni < 3; ni++)
          acc[mi * 3 + ni] = __builtin_amdgcn_mfma_f32_16x16x32_bf16(
              af[ks][mi], bfr[ks][ni], acc[mi * 3 + ni], 0, 0, 0);
    VMCNT0();
    BARRIER();
  }
  float bv[3];
#pragma unroll
  for (int ni = 0; ni < 3; ni++) bv[ni] = bias[n0 + wn + ni * 16 + l15];
#pragma unroll
  for (int mi = 0; mi < 2; mi++)
#pragma unroll
    for (int ni = 0; ni < 3; ni++)
#pragma unroll
      for (int r = 0; r < 4; r++) {
        int grow = m0 + wm + mi * 16 + quad * 4 + r;
        int gcol = n0 + wn + ni * 16 + l15;
        out[(size_t)grow * CDIM + gcol] = acc[mi * 3 + ni][r] + bv[ni];
      }
}

extern "C" void kernel_launch(void* const* d_in, const int* in_sizes, int n_in,
                              void* d_out, int out_size, void* d_ws, size_t ws_size,
                              hipStream_t stream) {
  const float* xq = (const float*)d_in[0];
  const float* xk = (const float*)d_in[1];
  const float* xv = (const float*)d_in[2];
  const float* wq = (const float*)d_in[3];
  const float* wk = (const float*)d_in[4];
  const float* wv = (const float*)d_in[5];
  const float* wp = (const float*)d_in[6];
  const float* bp = (const float*)d_in[7];
  float* out = (float*)d_out;

  char* p = (char*)d_ws;
  unsigned short* Xq = (unsigned short*)p; p += (size_t)XEL * 2;
  unsigned short* Xk = (unsigned short*)p; p += (size_t)XEL * 2;
  unsigned short* Xv = (unsigned short*)p; p += (size_t)XEL * 2;
  unsigned short* Wq = (unsigned short*)p; p += (size_t)WEL * 2;
  unsigned short* Wk = (unsigned short*)p; p += (size_t)WEL * 2;
  unsigned short* Wv = (unsigned short*)p; p += (size_t)WEL * 2;
  unsigned short* Wp = (unsigned short*)p; p += (size_t)WEL * 2;
  unsigned short* Qb = (unsigned short*)p; p += (size_t)XEL * 2;
  unsigned short* Kb = (unsigned short*)p; p += (size_t)XEL * 2;
  unsigned short* Vb = (unsigned short*)p; p += (size_t)XEL * 2;
  unsigned short* Cx = (unsigned short*)p; p += (size_t)XEL * 2;

  cast_all<<<(3 * X8 + 4 * W8) / 256, 256, 0, stream>>>(
      xq, xk, xv, wq, wk, wv, wp, Xq, Xk, Xv, Wq, Wk, Wv, Wp);

  gemm_qkv<<<768, 256, 0, stream>>>(
      Xq, Xk, Xv, Wq, Wk, Wv, Qb, Kb, Vb);

  attn_kernel<<<768, 256, 0, stream>>>(Qb, Kb, Vb, Cx);

  gemm_out<<<512, 256, 0, stream>>>(Cx, Wp, bp, out);
}

// Round 10
// 173.187 us; speedup vs baseline: 1.0423x; 1.0261x over previous
//
#include <hip/hip_runtime.h>
#include <hip/hip_bf16.h>

// Attention: xq/xk/xv [2,2048,768] f32, W* [768,768] f32 ([out,in]), bp [768] f32.
// Pipeline: fused cast->bf16, fused QKV NT-GEMM (r14 version: 128x96 tiles,
// 768 blocks = 3/CU balanced, 2-phase overlap schedule + T5 setprio;
// scale*log2e folded into Q; V computed TRANSPOSED via swapped operands),
// flash attention (r17 = r14 structure: 32x32 MFMA in-register P + overlap
// schedule, + T5 setprio around MFMA clusters, + v_cvt_pk_bf16_f32 pack),
// output NT-GEMM + bias (64x96 tiles, BK=128, overlap schedule + setprio).

#define NSEQ 2048
#define CDIM 768
#define NH   12
#define HD   64
#define MTOT 4096            // B*NSEQ
#define XEL  (MTOT*CDIM)     // 3145728
#define WEL  (CDIM*CDIM)     // 589824
#define X8   (XEL/8)         // 393216
#define W8   (WEL/8)         // 73728
#define QSCALE 0.18033688011112042f   // 0.125 * log2(e); scores consumed by exp2

typedef __attribute__((ext_vector_type(8))) short bf16x8;
typedef __attribute__((ext_vector_type(4))) float floatx4;
typedef __attribute__((ext_vector_type(16))) float floatx16;
typedef __attribute__((ext_vector_type(4))) unsigned int uintx4;

// scalar f32->bf16, round-half-up (2 VALU)
static __device__ __forceinline__ unsigned short f2bf(float f) {
  union { float f; unsigned int u; } v; v.f = f;
  return (unsigned short)((v.u + 0x8000u) >> 16);
}
// packed pair f32->bf16x2, round-half-up: 2 v_add + 1 v_perm
static __device__ __forceinline__ unsigned pk2bf(float a, float b) {
  unsigned ua = __float_as_uint(a) + 0x8000u;
  unsigned ub = __float_as_uint(b) + 0x8000u;
  return __builtin_amdgcn_perm(ub, ua, 0x07060302);  // {hi16(b), hi16(a)}
}
// packed pair f32->bf16x2 via HW cvt (1 VALU, RNE): dst = {bf16(a), bf16(b)}
static __device__ __forceinline__ unsigned cvtpk(float a, float b) {
  unsigned r;
  asm("v_cvt_pk_bf16_f32 %0, %1, %2" : "=v"(r) : "v"(a), "v"(b));
  return r;
}

static __device__ __forceinline__ void lds16(const void* g, void* l) {
  __builtin_amdgcn_global_load_lds(
      (const __attribute__((address_space(1))) unsigned int*)g,
      (__attribute__((address_space(3))) unsigned int*)l, 16, 0, 0);
}

// fences for the overlap schedules
#define LGKM0_SB()  do { asm volatile("s_waitcnt lgkmcnt(0)" ::: "memory"); \
                         __builtin_amdgcn_sched_barrier(0); } while (0)
#define VMCNT0()    asm volatile("s_waitcnt vmcnt(0)" ::: "memory")
#define BARRIER()   __builtin_amdgcn_s_barrier()
#define SB0()       __builtin_amdgcn_sched_barrier(0)
#define PRIO1()     __builtin_amdgcn_s_setprio(1)
#define PRIO0()     __builtin_amdgcn_s_setprio(0)

// ---------------- fused cast f32 -> bf16 (all 7 tensors, one launch) ----------
__global__ __launch_bounds__(256) void cast_all(
    const float* __restrict__ xq, const float* __restrict__ xk,
    const float* __restrict__ xv, const float* __restrict__ wq,
    const float* __restrict__ wk, const float* __restrict__ wv,
    const float* __restrict__ wp,
    unsigned short* __restrict__ Xq, unsigned short* __restrict__ Xk,
    unsigned short* __restrict__ Xv, unsigned short* __restrict__ Wq,
    unsigned short* __restrict__ Wk, unsigned short* __restrict__ Wv,
    unsigned short* __restrict__ Wp) {
  int i = blockIdx.x * 256 + threadIdx.x;
  const float* s; unsigned short* d; int off;
  if (i < 3 * X8) {
    int t = i / X8; off = i - t * X8;
    s = (t == 0) ? xq : (t == 1) ? xk : xv;
    d = (t == 0) ? Xq : (t == 1) ? Xk : Xv;
  } else {
    int j = i - 3 * X8; int t = j / W8; off = j - t * W8;
    s = (t == 0) ? wq : (t == 1) ? wk : (t == 2) ? wv : wp;
    d = (t == 0) ? Wq : (t == 1) ? Wk : (t == 2) ? Wv : Wp;
  }
  const float4* sp = (const float4*)s + (size_t)off * 2;
  float4 a = sp[0], b = sp[1];
  uint4 o;
  o.x = pk2bf(a.x, a.y); o.y = pk2bf(a.z, a.w);
  o.z = pk2bf(b.x, b.y); o.w = pk2bf(b.z, b.w);
  *(uint4*)(d + (size_t)off * 8) = o;
}

// ---------------- fused QKV NT-GEMM: r14 version (768 blocks, 3/CU) ---------
// z=0: Q = Xq Wq^T * QSCALE, tile 128m x 96n ; z=1: K; z=2: V^T = Wv Xv^T.
// 2-phase overlap: frag reads -> lgkm0+schedbar+barrier -> stage(k0+64) same
// buffer -> MFMA (setprio(1), hides staging latency) -> vmcnt0+barrier.
__global__ __launch_bounds__(256) void gemm_qkv(
    const unsigned short* __restrict__ Xq, const unsigned short* __restrict__ Xk,
    const unsigned short* __restrict__ Xv, const unsigned short* __restrict__ Wq,
    const unsigned short* __restrict__ Wk, const unsigned short* __restrict__ Wv,
    unsigned short* __restrict__ Qo, unsigned short* __restrict__ Ko,
    unsigned short* __restrict__ Vo) {
  int i0 = blockIdx.x;
  int mg = i0 & 7; int t0 = i0 >> 3;       // t0 in [0,96)
  int z = t0 % 3; int u = t0 / 3;          // u in [0,32)
  int xn = u & 7, ysub = u >> 3;           // 8 n-tiles x 4 m-subtiles
  int y = mg * 4 + ysub;                   // m-tile in [0,32)
  const unsigned short* A; const unsigned short* B; int am0, bn0, RA;
  if (z == 0)      { A = Xq; B = Wq; am0 = y * 128; bn0 = xn * 96; RA = 128; }
  else if (z == 1) { A = Xk; B = Wk; am0 = y * 128; bn0 = xn * 96; RA = 128; }
  else             { A = Wv; B = Xv; am0 = xn * 96; bn0 = y * 128; RA = 96; }
  __shared__ __align__(16) unsigned short S[224 * 64];
  int tid = threadIdx.x, lane = tid & 63, wave = tid >> 6;
  int quad = lane >> 4, l15 = lane & 15, l7 = l15 & 7;

  const unsigned short* gptr[7]; int ldo[7];
#pragma unroll
  for (int i = 0; i < 7; i++) {
    int idx = i * 256 + tid;
    int row = idx >> 3, c = (idx & 7) ^ (row & 7);
    gptr[i] = (row < RA ? A + (size_t)(am0 + row) * CDIM
                        : B + (size_t)(bn0 + row - RA) * CDIM) + c * 8;
    ldo[i] = idx * 8;
  }
  floatx4 acc[12];
#pragma unroll
  for (int i = 0; i < 12; i++) acc[i] = (floatx4){0.f, 0.f, 0.f, 0.f};

  // prologue: stage k0=0
#pragma unroll
  for (int i = 0; i < 7; i++) lds16(gptr[i], &S[ldo[i]]);
  VMCNT0();
  BARRIER();

  if (z < 2) {
    int wm = (wave >> 1) * 64, wn = (wave & 1) * 48;
    for (int k0 = 0; k0 < CDIM; k0 += 64) {
      bf16x8 af[2][4], bfr[2][3];
#pragma unroll
      for (int ks = 0; ks < 2; ks++) {
        int csw = ((ks * 4 + quad) ^ l7) * 8;
#pragma unroll
        for (int i = 0; i < 4; i++)
          af[ks][i] = *(const bf16x8*)&S[(wm + i * 16 + l15) * 64 + csw];
#pragma unroll
        for (int j = 0; j < 3; j++)
          bfr[ks][j] = *(const bf16x8*)&S[(128 + wn + j * 16 + l15) * 64 + csw];
      }
      LGKM0_SB();
      BARRIER();
      if (k0 + 64 < CDIM) {
#pragma unroll
        for (int i = 0; i < 7; i++) lds16(gptr[i] + k0 + 64, &S[ldo[i]]);
      }
      SB0();
      PRIO1();
#pragma unroll
      for (int ks = 0; ks < 2; ks++)
#pragma unroll
        for (int mi = 0; mi < 4; mi++)
#pragma unroll
          for (int ni = 0; ni < 3; ni++)
            acc[mi * 3 + ni] = __builtin_amdgcn_mfma_f32_16x16x32_bf16(
                af[ks][mi], bfr[ks][ni], acc[mi * 3 + ni], 0, 0, 0);
      PRIO0();
      VMCNT0();
      BARRIER();
    }
#pragma unroll
    for (int mi = 0; mi < 4; mi++)
#pragma unroll
      for (int ni = 0; ni < 3; ni++)
#pragma unroll
        for (int r = 0; r < 4; r++) {
          int grow = am0 + wm + mi * 16 + quad * 4 + r;
          int gcol = bn0 + wn + ni * 16 + l15;
          float v = acc[mi * 3 + ni][r];
          int b = grow >> 11, nq = grow & 2047, h = gcol >> 6, dd = gcol & 63;
          if (z == 0)
            Qo[((size_t)(b * NH + h) * NSEQ + nq) * HD + dd] = f2bf(v * QSCALE);
          else
            Ko[((size_t)(b * NH + h) * NSEQ + nq) * HD + dd] = f2bf(v);
        }
  } else {
    int wm = (wave & 1) * 48, wn = (wave >> 1) * 64;
    for (int k0 = 0; k0 < CDIM; k0 += 64) {
      bf16x8 af[2][3], bfr[2][4];
#pragma unroll
      for (int ks = 0; ks < 2; ks++) {
        int csw = ((ks * 4 + quad) ^ l7) * 8;
#pragma unroll
        for (int i = 0; i < 3; i++)
          af[ks][i] = *(const bf16x8*)&S[(wm + i * 16 + l15) * 64 + csw];
#pragma unroll
        for (int j = 0; j < 4; j++)
          bfr[ks][j] = *(const bf16x8*)&S[(96 + wn + j * 16 + l15) * 64 + csw];
      }
      LGKM0_SB();
      BARRIER();
      if (k0 + 64 < CDIM) {
#pragma unroll
        for (int i = 0; i < 7; i++) lds16(gptr[i] + k0 + 64, &S[ldo[i]]);
      }
      SB0();
      PRIO1();
#pragma unroll
      for (int ks = 0; ks < 2; ks++)
#pragma unroll
        for (int mi = 0; mi < 3; mi++)
#pragma unroll
          for (int ni = 0; ni < 4; ni++)
            acc[mi * 4 + ni] = __builtin_amdgcn_mfma_f32_16x16x32_bf16(
                af[ks][mi], bfr[ks][ni], acc[mi * 4 + ni], 0, 0, 0);
      PRIO0();
      VMCNT0();
      BARRIER();
    }
#pragma unroll
    for (int mi = 0; mi < 3; mi++)
#pragma unroll
      for (int ni = 0; ni < 4; ni++)
#pragma unroll
        for (int r = 0; r < 4; r++) {
          int o = am0 + wm + mi * 16 + quad * 4 + r;
          int mgl = bn0 + wn + ni * 16 + l15;
          int b = mgl >> 11, nq = mgl & 2047;
          Vo[((size_t)b * CDIM + o) * NSEQ + nq] = f2bf(acc[mi * 4 + ni][r]);
        }
  }
}

// ---------------- flash attention: r17 = r14 + setprio + cvt_pk --------------
// Q,K: [24][2048][64] bf16 (Q pre-scaled); Vt: [24][64][2048] bf16.
// ctx: [4096][768] bf16. 768 blocks x 256 thr = 4 waves:
//   wave = (half<<1)|qsub: qsub selects 32 q-rows, half selects kv half (1024).
// Single 8KB K + 8KB V buffer per half. Per tile: 16 frag ds_read -> lgkm0 +
// sched_barrier + s_barrier (all readers done) -> stage tile t+1 into the SAME
// buffer -> register-only compute (QK 32x32 MFMA, exp2, cvt_pk pack, permlane,
// PV; MFMA clusters setprio(1)-wrapped) hides the staging L2 latency ->
// vmcnt0 + s_barrier. P never touches LDS; l = VALU tree + one permlane swap.
// Max-free softmax => halves combine exactly through LDS (swizzled Obuf).
__global__ __launch_bounds__(256, 3) void attn_kernel(
    const unsigned short* __restrict__ Q, const unsigned short* __restrict__ K,
    const unsigned short* __restrict__ Vt, unsigned short* __restrict__ ctx) {
  int i0 = blockIdx.x;
  int xcd = i0 & 7; int t0 = i0 >> 3;
  int bh = xcd * 3 + (t0 >> 5);
  int qt = t0 & 31;
  int tid = threadIdx.x, lane = tid & 63, wave = tid >> 6;
  int half = wave >> 1, qsub = wave & 1;
  int l31 = lane & 31, hi = lane >> 5;
  __shared__ __align__(16) unsigned short Ks[2][64 * 64];
  __shared__ __align__(16) unsigned short Vs[2][64 * 64];
  __shared__ float Lbuf[64];

  const unsigned short* Qg = Q + ((size_t)bh * NSEQ + qt * 64 + qsub * 32) * HD;
  const unsigned short* Kg = K + ((size_t)bh * NSEQ + half * 1024) * HD;
  const unsigned short* Vg = Vt + (size_t)bh * HD * NSEQ + half * 1024;

  // Q fragments (B-operand): lane holds Q[q=l31][d = dchunk*16 + hi*8 + j]
  bf16x8 qf[4];
#pragma unroll
  for (int dc = 0; dc < 4; dc++)
    qf[dc] = *(const bf16x8*)(Qg + l31 * HD + dc * 16 + hi * 8);

  // K/V staging: each half's 128 threads stage 8KB K + 8KB V
  int tid2 = tid & 127;
  int kgo[4], vgo[4], ldst[4];
#pragma unroll
  for (int i = 0; i < 4; i++) {
    int idx = i * 128 + tid2;
    int R = idx >> 3, c = (idx & 7) ^ (R & 7);
    kgo[i] = R * HD + c * 8;
    vgo[i] = R * NSEQ + c * 8;
    ldst[i] = idx * 8;
  }
  unsigned short* Ksh = Ks[half];
  unsigned short* Vsh = Vs[half];

  floatx16 o[2];
#pragma unroll
  for (int dt = 0; dt < 2; dt++) o[dt] = (floatx16)(0.f);
  float l_acc = 0.f;

  // prologue: stage tile 0
#pragma unroll
  for (int i = 0; i < 4; i++) {
    lds16(Kg + kgo[i], &Ksh[ldst[i]]);
    lds16(Vg + vgo[i], &Vsh[ldst[i]]);
  }
  VMCNT0();
  BARRIER();

  for (int t = 0; t < 16; t++) {
    // (a) fragment reads of tile t
    bf16x8 kf[2][4];
#pragma unroll
    for (int kb = 0; kb < 2; kb++)
#pragma unroll
      for (int dc = 0; dc < 4; dc++) {
        int R = kb * 32 + l31, c = dc * 2 + hi;
        kf[kb][dc] = *(const bf16x8*)&Ksh[R * 64 + ((c ^ (R & 7)) * 8)];
      }
    bf16x8 vf[2][4];
#pragma unroll
    for (int dt = 0; dt < 2; dt++)
#pragma unroll
      for (int j = 0; j < 4; j++) {
        int R = dt * 32 + l31, c = j * 2 + hi;
        vf[dt][j] = *(const bf16x8*)&Vsh[R * 64 + ((c ^ (R & 7)) * 8)];
      }
    // (b) readers-done fence
    LGKM0_SB();
    BARRIER();
    // (c) stage tile t+1 into the same buffer (in flight across compute)
    if (t < 15) {
      int k0n = (t + 1) * 64;
#pragma unroll
      for (int i = 0; i < 4; i++) {
        lds16(Kg + (size_t)k0n * HD + kgo[i], &Ksh[ldst[i]]);
        lds16(Vg + k0n + vgo[i], &Vsh[ldst[i]]);
      }
    }
    SB0();
    // (d) register-only compute
#pragma unroll
    for (int kb = 0; kb < 2; kb++) {
      floatx16 st = (floatx16)(0.f);
      PRIO1();
#pragma unroll
      for (int dc = 0; dc < 4; dc++)
        st = __builtin_amdgcn_mfma_f32_32x32x16_bf16(kf[kb][dc], qf[dc], st, 0, 0, 0);
      PRIO0();
      // exp2 all 16 scores (max-free softmax)
      float p[16];
#pragma unroll
      for (int r = 0; r < 16; r++) p[r] = __builtin_exp2f(st[r]);
      // l: VALU tree sum of this lane's 16 values
      l_acc += ((p[0] + p[1]) + (p[2] + p[3])) + ((p[4] + p[5]) + (p[6] + p[7])) +
               (((p[8] + p[9]) + (p[10] + p[11])) + ((p[12] + p[13]) + (p[14] + p[15])));
      // pack pairs via HW cvt_pk (1 VALU each): w[i] = bf16{p[2i], p[2i+1]}
      unsigned w[8];
#pragma unroll
      for (int i = 0; i < 8; i++) w[i] = cvtpk(p[2 * i], p[2 * i + 1]);
      // permlane32_swap: build PV B-fragments (k = hi*8 + j within each kv16)
#pragma unroll
      for (int kvs = 0; kvs < 2; kvs++) {
        unsigned a0 = w[kvs * 4 + 0], b0 = w[kvs * 4 + 2];
        unsigned a1 = w[kvs * 4 + 1], b1 = w[kvs * 4 + 3];
        asm volatile("v_permlane32_swap_b32 %0, %1" : "+v"(a0), "+v"(b0));
        asm volatile("v_permlane32_swap_b32 %0, %1" : "+v"(a1), "+v"(b1));
        uintx4 pw; pw[0] = a0; pw[1] = a1; pw[2] = b0; pw[3] = b1;
        bf16x8 pb = *(bf16x8*)&pw;
        PRIO1();
#pragma unroll
        for (int dt = 0; dt < 2; dt++)
          o[dt] = __builtin_amdgcn_mfma_f32_32x32x16_bf16(
              vf[dt][kb * 2 + kvs], pb, o[dt], 0, 0, 0);
        PRIO0();
      }
    }
    // (e) stage-done fence (cheap: issued ~400 cyc ago)
    VMCNT0();
    BARRIER();
  }

  // complete l across lane halves: one permlane swap + add
  unsigned lu = __float_as_uint(l_acc), lv = __float_as_uint(l_acc);
  asm volatile("v_permlane32_swap_b32 %0, %1" : "+v"(lu), "+v"(lv));
  float lfull = __uint_as_float(lu) + __uint_as_float(lv);

  // in-block kv-half combine: half-1 -> LDS, half-0 adds + stores.
  // Obuf chunks XOR-swizzled by q (linear [64q][64d] f32 would be 32-way).
  float* Obuf = (float*)&Ks[0][0];   // 64q x 64d f32 = 16 KB (== Ks)
  int q = qsub * 32 + l31;
  if (half == 1) {
#pragma unroll
    for (int dt = 0; dt < 2; dt++)
#pragma unroll
      for (int rq = 0; rq < 4; rq++) {
        int ch = (dt * 8 + rq * 2 + hi) ^ (l31 & 15);
        floatx4 v4 = {o[dt][rq * 4 + 0], o[dt][rq * 4 + 1],
                      o[dt][rq * 4 + 2], o[dt][rq * 4 + 3]};
        *(floatx4*)&Obuf[q * 64 + ch * 4] = v4;
      }
    if (lane < 32) Lbuf[qsub * 32 + lane] = lfull;
  }
  __syncthreads();
  if (half == 0) {
    int b = bh / NH, h = bh - b * NH;
    float inv = 1.f / (lfull + Lbuf[q]);
    int qrow = qt * 64 + q;
#pragma unroll
    for (int dt = 0; dt < 2; dt++)
#pragma unroll
      for (int rq = 0; rq < 4; rq++) {
        int ch = (dt * 8 + rq * 2 + hi) ^ (l31 & 15);
        floatx4 ob = *(floatx4*)&Obuf[q * 64 + ch * 4];
        float v0 = (o[dt][rq * 4 + 0] + ob[0]) * inv;
        float v1 = (o[dt][rq * 4 + 1] + ob[1]) * inv;
        float v2 = (o[dt][rq * 4 + 2] + ob[2]) * inv;
        float v3 = (o[dt][rq * 4 + 3] + ob[3]) * inv;
        size_t gbase = (size_t)(b * NSEQ + qrow) * CDIM + h * HD +
                       dt * 32 + rq * 8 + hi * 4;
        *(uint2*)&ctx[gbase] = make_uint2(pk2bf(v0, v1), pk2bf(v2, v3));
      }
  }
}

// ------------- output NT-GEMM + bias, 64x96 tiles, BK=128, XCD-swizzled ------
// 2-phase overlap schedule + T5 setprio.
__global__ __launch_bounds__(256) void gemm_out(
    const unsigned short* __restrict__ A, const unsigned short* __restrict__ B,
    const float* __restrict__ bias, float* __restrict__ out) {
  int i0 = blockIdx.x;                  // 512 blocks = 2/CU
  int mg = i0 & 7; int t0 = i0 >> 3;    // t0 in [0,64)
  int n0 = (t0 & 7) * 96;
  int m0 = (mg * 8 + (t0 >> 3)) * 64;
  __shared__ __align__(16) unsigned short S[160 * 128];  // A rows 0..63, B rows 64..159
  int tid = threadIdx.x, lane = tid & 63, wave = tid >> 6;
  int quad = lane >> 4, l15 = lane & 15, l7 = l15 & 7;
  int wm = (wave >> 1) * 32, wn = (wave & 1) * 48;
  floatx4 acc[6];
#pragma unroll
  for (int i = 0; i < 6; i++) acc[i] = (floatx4){0.f, 0.f, 0.f, 0.f};

  int sro[10]; const unsigned short* sgp[10];
#pragma unroll
  for (int i = 0; i < 10; i++) {       // 160 rows x 16 chunks = 2560 = 10*256
    int idx = i * 256 + tid;
    int R = idx >> 4, c4 = idx & 15;
    int cs = (c4 & 8) | ((c4 & 7) ^ (R & 7));
    sgp[i] = ((R < 64) ? A + (size_t)(m0 + R) * CDIM
                       : B + (size_t)(n0 + R - 64) * CDIM) + cs * 8;
    sro[i] = idx * 8;
  }
  // prologue: stage k0=0
#pragma unroll
  for (int i = 0; i < 10; i++) lds16(sgp[i], &S[sro[i]]);
  VMCNT0();
  BARRIER();

  for (int k0 = 0; k0 < CDIM; k0 += 128) {
    bf16x8 af[4][2], bfr[4][3];
#pragma unroll
    for (int ks = 0; ks < 4; ks++) {
      int c = ks * 4 + quad;
      int csw = ((c & 8) | ((c & 7) ^ l7)) * 8;
#pragma unroll
      for (int i = 0; i < 2; i++)
        af[ks][i] = *(const bf16x8*)&S[(wm + i * 16 + l15) * 128 + csw];
#pragma unroll
      for (int j = 0; j < 3; j++)
        bfr[ks][j] = *(const bf16x8*)&S[(64 + wn + j * 16 + l15) * 128 + csw];
    }
    LGKM0_SB();
    BARRIER();
    if (k0 + 128 < CDIM) {
#pragma unroll
      for (int i = 0; i < 10; i++) lds16(sgp[i] + k0 + 128, &S[sro[i]]);
    }
    SB0();
    PRIO1();
#pragma unroll
    for (int ks = 0; ks < 4; ks++)
#pragma unroll
      for (int mi = 0; mi < 2; mi++)
#pragma unroll
        for (int ni = 0; ni < 3; ni++)
          acc[mi * 3 + ni] = __builtin_amdgcn_mfma_f32_16x16x32_bf16(
              af[ks][mi], bfr[ks][ni], acc[mi * 3 + ni], 0, 0, 0);
    PRIO0();
    VMCNT0();
    BARRIER();
  }
  float bv[3];
#pragma unroll
  for (int ni = 0; ni < 3; ni++) bv[ni] = bias[n0 + wn + ni * 16 + l15];
#pragma unroll
  for (int mi = 0; mi < 2; mi++)
#pragma unroll
    for (int ni = 0; ni < 3; ni++)
#pragma unroll
      for (int r = 0; r < 4; r++) {
        int grow = m0 + wm + mi * 16 + quad * 4 + r;
        int gcol = n0 + wn + ni * 16 + l15;
        out[(size_t)grow * CDIM + gcol] = acc[mi * 3 + ni][r] + bv[ni];
      }
}

extern "C" void kernel_launch(void* const* d_in, const int* in_sizes, int n_in,
                              void* d_out, int out_size, void* d_ws, size_t ws_size,
                              hipStream_t stream) {
  const float* xq = (const float*)d_in[0];
  const float* xk = (const float*)d_in[1];
  const float* xv = (const float*)d_in[2];
  const float* wq = (const float*)d_in[3];
  const float* wk = (const float*)d_in[4];
  const float* wv = (const float*)d_in[5];
  const float* wp = (const float*)d_in[6];
  const float* bp = (const float*)d_in[7];
  float* out = (float*)d_out;

  char* p = (char*)d_ws;
  unsigned short* Xq = (unsigned short*)p; p += (size_t)XEL * 2;
  unsigned short* Xk = (unsigned short*)p; p += (size_t)XEL * 2;
  unsigned short* Xv = (unsigned short*)p; p += (size_t)XEL * 2;
  unsigned short* Wq = (unsigned short*)p; p += (size_t)WEL * 2;
  unsigned short* Wk = (unsigned short*)p; p += (size_t)WEL * 2;
  unsigned short* Wv = (unsigned short*)p; p += (size_t)WEL * 2;
  unsigned short* Wp = (unsigned short*)p; p += (size_t)WEL * 2;
  unsigned short* Qb = (unsigned short*)p; p += (size_t)XEL * 2;
  unsigned short* Kb = (unsigned short*)p; p += (size_t)XEL * 2;
  unsigned short* Vb = (unsigned short*)p; p += (size_t)XEL * 2;
  unsigned short* Cx = (unsigned short*)p; p += (size_t)XEL * 2;

  cast_all<<<(3 * X8 + 4 * W8) / 256, 256, 0, stream>>>(
      xq, xk, xv, wq, wk, wv, wp, Xq, Xk, Xv, Wq, Wk, Wv, Wp);

  gemm_qkv<<<768, 256, 0, stream>>>(
      Xq, Xk, Xv, Wq, Wk, Wv, Qb, Kb, Vb);

  attn_kernel<<<768, 256, 0, stream>>>(Qb, Kb, Vb, Cx);

  gemm_out<<<512, 256, 0, stream>>>(Cx, Wp, bp, out);
}